// Round 1
// baseline (307.896 us; speedup 1.0000x reference)
//
#include <hip/hip_runtime.h>

// Embedding two-field gather + dot product.
// x: (B,2) int32 indices (field 0 in [0,100000), field 1 offset by +100000)
// table: (1100000, 64) float32
// out: (B,) float32, out[b] = dot(table[x[b,0]], table[x[b,1]+100000])
//
// Layout: 8 lanes per sample. Each lane loads TWO float4 per row
// (offsets sub and sub+8) -> 4 independent global_load_dwordx4 in
// flight per lane (2x the MLP of the 16-lane version), half the wave
// count, 3 shuffle steps instead of 4. Per-wave access pattern is 8
// samples x 2 x 128 B contiguous segments -> fully coalesced.
// Index math kept in 32-bit: max float4 index = 1.1M*16 = 17.6M < 2^31,
// max byte offset 282 MB < 2^31.

#define FIELD1_OFFSET 100000

__global__ __launch_bounds__(256) void MF_84722524880963_kernel(
        const int* __restrict__ x,
        const float* __restrict__ table,
        float* __restrict__ out,
        int B) {
    int gid = blockIdx.x * blockDim.x + threadIdx.x;
    int s   = gid >> 3;    // sample index (8 lanes per sample)
    int sub = gid & 7;     // lane within sample
    if (s >= B) return;

    int2 xi = ((const int2*)x)[s];            // both indices in one 8 B load
    int ui = xi.x * 16 + sub;                  // float4 index of row u
    int vi = (xi.y + FIELD1_OFFSET) * 16 + sub;

    const float4* t4 = (const float4*)table;  // row = 16 float4s
    // 4 independent 16 B loads -> all in flight before first use
    float4 a0 = t4[ui];
    float4 a1 = t4[ui + 8];
    float4 b0 = t4[vi];
    float4 b1 = t4[vi + 8];

    float p = a0.x * b0.x + a0.y * b0.y + a0.z * b0.z + a0.w * b0.w
            + a1.x * b1.x + a1.y * b1.y + a1.z * b1.z + a1.w * b1.w;

    // reduce across the 8-lane segment
    p += __shfl_down(p, 4, 8);
    p += __shfl_down(p, 2, 8);
    p += __shfl_down(p, 1, 8);

    if (sub == 0) out[s] = p;
}

extern "C" void kernel_launch(void* const* d_in, const int* in_sizes, int n_in,
                              void* d_out, int out_size, void* d_ws, size_t ws_size,
                              hipStream_t stream) {
    const int* x = (const int*)d_in[0];          // (B,2) int32
    const float* table = (const float*)d_in[1];  // (1100000, 64) fp32
    float* out = (float*)d_out;                  // (B,) fp32
    int B = in_sizes[0] / 2;                     // 16384

    int threads = B * 8;                         // 8 lanes per sample
    int block = 256;
    int grid = (threads + block - 1) / block;    // 512 blocks
    MF_84722524880963_kernel<<<grid, block, 0, stream>>>(x, table, out, B);
}